// Round 11
// baseline (219.942 us; speedup 1.0000x reference)
//
#include <hip/hip_runtime.h>
#include <hip/hip_bf16.h>

#define D 256
#define TEMP_INV 20.0f        // 1 / 0.05
#define K_EXP2 28.85390081777927f   // 20 / ln(2): e^(20x) = 2^(K_EXP2*x)
#define NJ 16                 // 128-col tiles per colgroup (2048 cols per block)

typedef __attribute__((ext_vector_type(8))) short bf16x8s;  // 8 bf16 in 4 VGPRs
typedef __attribute__((ext_vector_type(4))) float f32x4;

// ---- helpers ----------------------------------------------------------------
__device__ __forceinline__ unsigned short f2bf(float f) {
  unsigned u = __float_as_uint(f);
  unsigned r = u + 0x7FFFu + ((u >> 16) & 1u);
  return (unsigned short)(r >> 16);
}

// ---- kernel 1: fused row L2-normalize f32 -> bf16 (3 inputs) + zero rowsum --
__global__ __launch_bounds__(256) void nce_normalize(const float* __restrict__ anc,
                                                     const float* __restrict__ pos,
                                                     const float* __restrict__ neg,
                                                     unsigned short* __restrict__ An,
                                                     unsigned short* __restrict__ Tn,
                                                     float* __restrict__ rowsum,
                                                     int B) {
  int zi = blockIdx.x * 256 + threadIdx.x;
  if (blockIdx.x < (B + 255) / 256 && zi < B) rowsum[zi] = 0.0f;

  const int lane = threadIdx.x & 63;
  const int wid  = threadIdx.x >> 6;
  const int sub  = lane >> 4, lr = lane & 15;
  int row = blockIdx.x * 16 + wid * 4 + sub;

  const float* src;
  unsigned short* dst;
  int r2;
  if (row < B)          { src = anc; dst = An; r2 = row; }
  else if (row < 2 * B) { src = pos; dst = Tn; r2 = row - B; }
  else                  { src = neg; dst = Tn + (size_t)B * D; r2 = row - 2 * B; }

  const float4* sp = reinterpret_cast<const float4*>(src) + (size_t)r2 * (D / 4);
  float4 v[4];
#pragma unroll
  for (int c = 0; c < 4; ++c) v[c] = sp[lr + c * 16];
  float ss = 0.0f;
#pragma unroll
  for (int c = 0; c < 4; ++c)
    ss += v[c].x * v[c].x + v[c].y * v[c].y + v[c].z * v[c].z + v[c].w * v[c].w;
  ss += __shfl_xor(ss, 1, 64);
  ss += __shfl_xor(ss, 2, 64);
  ss += __shfl_xor(ss, 4, 64);
  ss += __shfl_xor(ss, 8, 64);
  float inv = rsqrtf(fmaxf(ss, 1e-24f));
  ushort4* dp = reinterpret_cast<ushort4*>(dst) + (size_t)r2 * (D / 4);
#pragma unroll
  for (int c = 0; c < 4; ++c) {
    ushort4 o;
    o.x = f2bf(v[c].x * inv);
    o.y = f2bf(v[c].y * inv);
    o.z = f2bf(v[c].z * inv);
    o.w = f2bf(v[c].w * inv);
    dp[lr + c * 16] = o;
  }
}

// ---- kernel 2: fully-async MFMA GEMM — no LDS, no barriers ------------------
// Each wave free-runs: A panel (64 rows x 256 K) in VGPRs; B fragments loaded
// DIRECTLY from global (L2-resident: 1MB colgroup per XCD) into a 2-deep
// register double-buffer. Per K-step (BK=32): 16 independent 16x16x32 MFMAs
// consume bR[kt&1], then 4 global_load_dwordx4 refill it for step kt+2.
// The compiler inserts precise per-use vmcnt waits (G7); no s_barrier, no
// s_waitcnt asm, no LDS choreography — removing the stage+barrier critical
// path that pinned R5/R8/R10 at ~70us regardless of BK/split (m233 analog).
// Coalescing: a wave's 64x16B per load instr = 16 full 64B lines (lanes
// g=0..3 of each r cover one line). L2 dup cost (waves with same wc): ~2x,
// ~20 TB/s < 34.5 TB/s ceiling.
// VGPR budget @2 blocks/CU (256/wave): aF 128 + bR 32 + acc 64(AGPR) +
// rs 16 + addr/misc ~14 = ~254.
__global__ __launch_bounds__(256, 2) void nce_scores(const unsigned short* __restrict__ A,
                                                     const unsigned short* __restrict__ T,
                                                     float* __restrict__ rowsum,
                                                     float* __restrict__ diag) {
  const int tid  = threadIdx.x;
  const int lane = tid & 63;
  const int wid  = __builtin_amdgcn_readfirstlane(tid >> 6);
  const int wr = wid >> 1, wc = wid & 1;
  const int row0 = blockIdx.y * 128;
  const int cg   = blockIdx.x;              // colgroup: cols [cg*2048, +2048)
  const int r = lane & 15, g = lane >> 4;

  // ---- per-lane B fragment base pointers (j=0), n = 0..3 ----
  // frag (n) at j,kt: B[cg*2048 + j*128 + wc*64 + n*16 + r][kt*32 + g*8 ..+8]
  // byte addr = base_n + j*65536 + kt*64   (kt*64 folds into the load imm)
  const unsigned char* bPtr[4];
#pragma unroll
  for (int n = 0; n < 4; ++n)
    bPtr[n] = (const unsigned char*)T +
              (((size_t)(cg * 2048 + wc * 64 + n * 16 + r)) << 9) + g * 16;

  // ---- A panel into registers (64 rows x 256 K per wave) ----
  const unsigned short* aPtr = A + (size_t)(row0 + wr * 64 + r) * D + g * 8;
  bf16x8s aF[4][8];
#pragma unroll
  for (int m = 0; m < 4; ++m)
#pragma unroll
    for (int t = 0; t < 8; ++t)
      aF[m][t] = *reinterpret_cast<const bf16x8s*>(aPtr + (size_t)m * 16 * D + t * 32);

  float rs[4][4];
#pragma unroll
  for (int m = 0; m < 4; ++m)
#pragma unroll
    for (int reg = 0; reg < 4; ++reg) rs[m][reg] = 0.0f;

  // ---- register double-buffer prologue: steps (j=0,kt=0) and (j=0,kt=1) ----
  bf16x8s bR[2][4];
#pragma unroll
  for (int n = 0; n < 4; ++n)
    bR[0][n] = *reinterpret_cast<const bf16x8s*>(bPtr[n]);
#pragma unroll
  for (int n = 0; n < 4; ++n)
    bR[1][n] = *reinterpret_cast<const bf16x8s*>(bPtr[n] + 64);

  for (int j = 0; j < NJ; ++j) {
    f32x4 acc[4][4];
#pragma unroll
    for (int m = 0; m < 4; ++m)
#pragma unroll
      for (int n = 0; n < 4; ++n) acc[m][n] = (f32x4)0.0f;

    const bool lastJ = (j == NJ - 1);

#pragma unroll
    for (int kt = 0; kt < 8; ++kt) {
      // consume bR[kt&1] (step kt), 16 independent MFMAs
#pragma unroll
      for (int m = 0; m < 4; ++m)
#pragma unroll
        for (int n = 0; n < 4; ++n)
          acc[m][n] = __builtin_amdgcn_mfma_f32_16x16x32_bf16(
              aF[m][kt], bR[kt & 1][n], acc[m][n], 0, 0, 0);
      // refill bR[kt&1] with step kt+2 (kt>=6 -> next j-tile, +65536)
      if (!lastJ || kt < 6) {
        const int off = (kt >= 6) ? (65536 + ((kt - 6) << 6)) : ((kt + 2) << 6);
#pragma unroll
        for (int n = 0; n < 4; ++n)
          bR[kt & 1][n] = *reinterpret_cast<const bf16x8s*>(bPtr[n] + off);
      }
    }

    // ---- per-tile epilogue: VALU only (exp partials in regs) ----
    // C/D layout: col = lane&15 (=r), row = g*4 + reg  [measured m89]
    const bool diagTile = (cg * NJ + j == (int)blockIdx.y);
#pragma unroll
    for (int m = 0; m < 4; ++m) {
#pragma unroll
      for (int reg = 0; reg < 4; ++reg) {
        float s = 0.0f;
#pragma unroll
        for (int n = 0; n < 4; ++n)
          s += __builtin_amdgcn_exp2f(acc[m][n][reg] * K_EXP2);   // e^(20*score)
        rs[m][reg] += s;
        // diagonal raw score: row==col when wr==wc, n==m, r==g*4+reg
        if (diagTile && wr == wc && r == g * 4 + reg)
          diag[row0 + wr * 64 + m * 16 + r] = acc[m][m][reg];
      }
    }

    // advance B pointers to next j-tile (+128 rows = 65536B)
#pragma unroll
    for (int n = 0; n < 4; ++n) bPtr[n] += 65536;
  }

  // ---- once per block: reduce 16-lane groups, atomic into global rowsum ----
#pragma unroll
  for (int m = 0; m < 4; ++m) {
#pragma unroll
    for (int reg = 0; reg < 4; ++reg) {
      float s = rs[m][reg];
      s += __shfl_xor(s, 1, 64);
      s += __shfl_xor(s, 2, 64);
      s += __shfl_xor(s, 4, 64);
      s += __shfl_xor(s, 8, 64);
      if (r == 0) atomicAdd(&rowsum[row0 + wr * 64 + m * 16 + g * 4 + reg], s);
    }
  }
}

// ---- kernel 3: loss_i = log(rowsum_i) - diag_i*20; mean -> scalar -----------
__global__ __launch_bounds__(1024) void nce_finalize(const float* __restrict__ rowsum,
                                                     const float* __restrict__ diag,
                                                     float* __restrict__ out, int n) {
  __shared__ float red[16];
  float s = 0.0f;
  for (int i = threadIdx.x; i < n; i += 1024)
    s += logf(rowsum[i]) - diag[i] * TEMP_INV;
#pragma unroll
  for (int m = 1; m < 64; m <<= 1) s += __shfl_xor(s, m, 64);
  if ((threadIdx.x & 63) == 0) red[threadIdx.x >> 6] = s;
  __syncthreads();
  if (threadIdx.x == 0) {
    float t = 0.0f;
#pragma unroll
    for (int i = 0; i < 16; ++i) t += red[i];
    out[0] = t / (float)n;
  }
}

// ---- launch -----------------------------------------------------------------
extern "C" void kernel_launch(void* const* d_in, const int* in_sizes, int n_in,
                              void* d_out, int out_size, void* d_ws, size_t ws_size,
                              hipStream_t stream) {
  const float* anc = (const float*)d_in[0];
  const float* pos = (const float*)d_in[1];
  const float* neg = (const float*)d_in[2];
  const int B  = in_sizes[0] / D;   // 8192
  const int N2 = 2 * B;             // 16384

  char* ws = (char*)d_ws;
  unsigned short* An = (unsigned short*)ws;                          // B*D bf16
  unsigned short* Tn = (unsigned short*)(ws + (size_t)B * D * 2);    // 2B*D bf16
  float* rowsum = (float*)(ws + (size_t)B * D * 2 + (size_t)N2 * D * 2);
  float* diag   = rowsum + B;

  nce_normalize<<<3 * B / 16, 256, 0, stream>>>(anc, pos, neg, An, Tn, rowsum, B);

  dim3 grid(N2 / (NJ * 128), B / 128);   // (8, 64) = 512 blocks = 2/CU
  nce_scores<<<grid, 256, 0, stream>>>(An, Tn, rowsum, diag);

  nce_finalize<<<1, 1024, 0, stream>>>(rowsum, diag, (float*)d_out, B);
}